// Round 7
// baseline (296.213 us; speedup 1.0000x reference)
//
#include <hip/hip_runtime.h>
#include <hip/hip_bf16.h>
#include <cstdint>
#include <cstddef>

#define NHEADS 16
#define DHEAD 64
#define BATCH 4
#define SEQ 2048
// M = 8192, D = 1024

typedef __attribute__((ext_vector_type(8))) __bf16 bf16x8;
typedef __attribute__((ext_vector_type(4))) float f32x4;

__device__ __forceinline__ unsigned short f2bf(float f) {
  union { float f; unsigned u; } v; v.f = f;
  unsigned r = v.u + 0x7FFFu + ((v.u >> 16) & 1u);  // RNE
  return (unsigned short)(r >> 16);
}

// packed f32x2 -> bf16x2 (RNE); compiler pattern-matches to v_cvt_pk_bf16_f32
__device__ __forceinline__ unsigned pk2(float x, float y) {
  union { __hip_bfloat162 h; unsigned u; } c;
  c.h = __float22bfloat162_rn(make_float2(x, y));
  return c.u;
}

// ---------------- f32 -> bf16 convert (x4 vectorized) ----------------
__global__ void cvt_bf16(const float* __restrict__ in, unsigned short* __restrict__ out, int n4) {
  int i = blockIdx.x * blockDim.x + threadIdx.x;
  int stride = gridDim.x * blockDim.x;
  for (; i < n4; i += stride) {
    float4 f = ((const float4*)in)[i];
    uint2 o;
    o.x = pk2(f.x, f.y);
    o.y = pk2(f.z, f.w);
    ((uint2*)out)[i] = o;
  }
}

// ---------------- QKV GEMM: bf16 xb [8192,1024] (DMA) @ f32 w_qkv [3072,1024]^T + bias ----------------
// R6 structure with BM=256: single-buffer 2-barrier loop, A (x bf16, 256 rows)
// via 4x global_load_lds; B (weights f32, 128 rows) cvt_pk-staged in the
// barrier window (unchanged). 32 MFMA/wave per K-step (2x R6) against the same
// per-iteration staging cost -> latency-bound fraction halves.
// XCD remap: 768 blocks = 8 XCDs x (3 N x 32 M), m-fastest-within-3: weight
// slice (1.5 MiB f32) L2-resident per XCD; x panel (512 KiB) reused 3x.
__global__ __launch_bounds__(256, 2) void gemm_qkv(
    const unsigned short* __restrict__ A,    // xb bf16 [8192][1024]
    const float* __restrict__ Bw,            // w_qkv f32 [3072][1024]
    const float* __restrict__ bias,          // [3072]
    unsigned short* __restrict__ qb,         // [64][2048][64]  (q pre-scaled by 0.1803369)
    unsigned short* __restrict__ kb,         // [64][2048][64]
    unsigned short* __restrict__ vt) {       // [64][64][2048]  (V^T)
  __shared__ unsigned short As[256 * 32];    // 16 KiB; unpadded: DMA dest = base + lane*16B
  __shared__ unsigned short Bs[128 * 32];    // 8 KiB
  const int t = threadIdx.x;
  const int lane = t & 63;
  const int wv = t >> 6;
  const int wm = wv >> 1, wn = wv & 1;       // wm in {0,1}: 128-row half; wn: 64-col half
  const int quad = lane >> 4, l15 = lane & 15;
  // XCD-aware remap: 768 blocks = 8 XCDs x (3 N x 32 M)
  const int orig = blockIdx.x;
  const int xcd = orig & 7;
  const int idx = orig >> 3;            // 0..95
  const int bN = (xcd * 3 + (idx % 3)) * 128;
  const int bM = (idx / 3) * 256;
  const int r0 = t >> 2;        // 0..63
  const int c0 = (t & 3) * 8;   // 0,8,16,24

  f32x4 acc[8][4];
#pragma unroll
  for (int i = 0; i < 8; i++)
#pragma unroll
    for (int j = 0; j < 4; j++) acc[i][j] = f32x4{0.f, 0.f, 0.f, 0.f};

  const unsigned short* aS0 = A + (size_t)(bM + r0) * 1024 + c0;        // + k0
  const unsigned short* aS1 = A + (size_t)(bM + 64 + r0) * 1024 + c0;
  const unsigned short* aS2 = A + (size_t)(bM + 128 + r0) * 1024 + c0;
  const unsigned short* aS3 = A + (size_t)(bM + 192 + r0) * 1024 + c0;
  const size_t bR0 = (size_t)(bN + r0) * 1024 + c0;
  const size_t bR1 = (size_t)(bN + 64 + r0) * 1024 + c0;

  for (int kt = 0; kt < 32; ++kt) {
    const int k0 = kt * 32;
    __syncthreads();  // previous iteration's LDS readers done
    __builtin_amdgcn_global_load_lds(
        (const __attribute__((address_space(1))) void*)(aS0 + k0),
        (__attribute__((address_space(3))) void*)(&As[r0 * 32 + c0]), 16, 0, 0);
    __builtin_amdgcn_global_load_lds(
        (const __attribute__((address_space(1))) void*)(aS1 + k0),
        (__attribute__((address_space(3))) void*)(&As[(64 + r0) * 32 + c0]), 16, 0, 0);
    __builtin_amdgcn_global_load_lds(
        (const __attribute__((address_space(1))) void*)(aS2 + k0),
        (__attribute__((address_space(3))) void*)(&As[(128 + r0) * 32 + c0]), 16, 0, 0);
    __builtin_amdgcn_global_load_lds(
        (const __attribute__((address_space(1))) void*)(aS3 + k0),
        (__attribute__((address_space(3))) void*)(&As[(192 + r0) * 32 + c0]), 16, 0, 0);
    float4 b00 = *(const float4*)&Bw[bR0 + k0];
    float4 b01 = *(const float4*)&Bw[bR0 + k0 + 4];
    float4 b10 = *(const float4*)&Bw[bR1 + k0];
    float4 b11 = *(const float4*)&Bw[bR1 + k0 + 4];
    uint4 w0, w1;
    w0.x = pk2(b00.x, b00.y); w0.y = pk2(b00.z, b00.w);
    w0.z = pk2(b01.x, b01.y); w0.w = pk2(b01.z, b01.w);
    w1.x = pk2(b10.x, b10.y); w1.y = pk2(b10.z, b10.w);
    w1.z = pk2(b11.x, b11.y); w1.w = pk2(b11.z, b11.w);
    *(uint4*)&Bs[r0 * 32 + c0] = w0;
    *(uint4*)&Bs[(64 + r0) * 32 + c0] = w1;
    __syncthreads();  // drains DMA (vmcnt) + LDS writes (lgkm)

    bf16x8 af[8], bf[4];
#pragma unroll
    for (int mi = 0; mi < 8; mi++)
      af[mi] = *(const bf16x8*)&As[(wm * 128 + mi * 16 + l15) * 32 + quad * 8];
#pragma unroll
    for (int ni = 0; ni < 4; ni++)
      bf[ni] = *(const bf16x8*)&Bs[(wn * 64 + ni * 16 + l15) * 32 + quad * 8];
#pragma unroll
    for (int mi = 0; mi < 8; mi++)
#pragma unroll
      for (int ni = 0; ni < 4; ni++)
        acc[mi][ni] = __builtin_amdgcn_mfma_f32_16x16x32_bf16(af[mi], bf[ni], acc[mi][ni], 0, 0, 0);
  }

  // epilogue: C row = bM+wm*128+mi*16+quad*4+reg, col = bN+wn*64+ni*16+l15
#pragma unroll
  for (int mi = 0; mi < 8; mi++) {
#pragma unroll
    for (int ni = 0; ni < 4; ni++) {
      const int n_col = bN + wn * 64 + ni * 16 + l15;
      const int m0 = bM + wm * 128 + mi * 16 + quad * 4;  // multiple of 4; all 4 rows same batch
      const float bv = bias[n_col];
      const int s = n_col >> 10;          // wave-uniform (16-col groups aligned)
      const int rem = n_col & 1023;
      const int h = rem >> 6, d = rem & 63;
      const int b = m0 >> 11;
      const int nn = m0 & 2047;
      const int bh = b * 16 + h;
      if (s == 2) {
        ushort4 o;
        o.x = f2bf(acc[mi][ni][0] + bv);
        o.y = f2bf(acc[mi][ni][1] + bv);
        o.z = f2bf(acc[mi][ni][2] + bv);
        o.w = f2bf(acc[mi][ni][3] + bv);
        *(ushort4*)&vt[((size_t)bh * 64 + d) * 2048 + nn] = o;
      } else {
        unsigned short* dst = (s == 0) ? qb : kb;
        // q scale = 1/8 (1/sqrt(dh)) * log2(e), so attn uses exp2 directly
        const float scale = (s == 0) ? 0.18033688f : 1.0f;
#pragma unroll
        for (int r = 0; r < 4; r++) {
          float v = (acc[mi][ni][r] + bv) * scale;
          dst[((size_t)bh * 2048 + nn + r) * 64 + d] = f2bf(v);
        }
      }
    }
  }
}

// ---------------- Flash attention: per (bh, 128 q-rows) block ----------------
// Proven R1 structure (passed @94us): single-buffer, two __syncthreads per kt.
// XCD remap: each XCD owns 8 bh x 16 q-blocks, q-fastest -> each bh's K/V
// (512 KiB) is fetched by exactly one XCD and stays L2-resident.
__global__ __launch_bounds__(256, 4) void attn(const unsigned short* __restrict__ qb,
                                               const unsigned short* __restrict__ kb,
                                               const unsigned short* __restrict__ vt,
                                               unsigned short* __restrict__ ob) {
  __shared__ unsigned short Ks[64 * 64];      // [key][d-group swizzled]
  __shared__ unsigned short Vs[64 * 64];      // [d][key-group swizzled]
  __shared__ unsigned short Ps[4][2][16 * 72];
  // XCD-aware remap: 1024 blocks = 8 XCDs x (8 bh x 16 q)
  const int orig = blockIdx.x;
  const int xcd = orig & 7;
  const int idx = orig >> 3;            // 0..127
  const int bh = xcd * 8 + (idx >> 4);  // 0..63
  const int q0 = (idx & 15) * 128;
  const int t = threadIdx.x, lane = t & 63, wv = t >> 6;
  const int quad = lane >> 4, l15 = lane & 15;
  const int ri = lane >> 3;    // 0..7: row within an 8-row DMA group
  const int g = lane & 7;      // 0..7: 16B group within a row
  const int sg = g ^ ri;       // swizzled source group

  // Q fragments for both 16-row groups, direct from global (B-operand layout)
  bf16x8 qf0[2], qf1[2];
#pragma unroll
  for (int grp = 0; grp < 2; grp++) {
    const size_t qbase = ((size_t)bh * 2048 + q0 + wv * 32 + grp * 16 + l15) * 64 + quad * 8;
    qf0[grp] = *(const bf16x8*)&qb[qbase];
    qf1[grp] = *(const bf16x8*)&qb[qbase + 32];
  }

  // DMA sources: wave wv loads rows [wv*16, wv*16+16) of each 64x64 tile
  const int rb0 = wv * 16;
  const int rb1 = wv * 16 + 8;
  const unsigned short* kS0 = kb + ((size_t)bh * 2048 + rb0 + ri) * 64 + sg * 8;  // +kt*4096
  const unsigned short* kS1 = kb + ((size_t)bh * 2048 + rb1 + ri) * 64 + sg * 8;
  const unsigned short* vS0 = vt + ((size_t)bh * 64 + rb0 + ri) * 2048 + sg * 8;  // +kt*64
  const unsigned short* vS1 = vt + ((size_t)bh * 64 + rb1 + ri) * 2048 + sg * 8;

  // lane-constant swizzled fragment read offsets (elements)
  const int o0 = (quad ^ (l15 & 7)) * 8;
  const int o1 = ((quad + 4) ^ (l15 & 7)) * 8;

  // all-ones B fragment for the l row-sum MFMA
  bf16x8 ones;
#pragma unroll
  for (int i = 0; i < 8; i++) ones[i] = (__bf16)1.0f;

  f32x4 acco[2][4];
#pragma unroll
  for (int grp = 0; grp < 2; grp++)
#pragma unroll
    for (int i = 0; i < 4; i++) acco[grp][i] = f32x4{0.f, 0.f, 0.f, 0.f};
  f32x4 lsum[2];
  lsum[0] = f32x4{0.f, 0.f, 0.f, 0.f};
  lsum[1] = f32x4{0.f, 0.f, 0.f, 0.f};

  for (int kt = 0; kt < 32; ++kt) {
    __syncthreads();  // previous iteration's readers done before DMA overwrites
    __builtin_amdgcn_global_load_lds(
        (const __attribute__((address_space(1))) void*)(kS0 + (size_t)kt * 4096),
        (__attribute__((address_space(3))) void*)(&Ks[rb0 * 64]), 16, 0, 0);
    __builtin_amdgcn_global_load_lds(
        (const __attribute__((address_space(1))) void*)(kS1 + (size_t)kt * 4096),
        (__attribute__((address_space(3))) void*)(&Ks[rb1 * 64]), 16, 0, 0);
    __builtin_amdgcn_global_load_lds(
        (const __attribute__((address_space(1))) void*)(vS0 + (size_t)kt * 64),
        (__attribute__((address_space(3))) void*)(&Vs[rb0 * 64]), 16, 0, 0);
    __builtin_amdgcn_global_load_lds(
        (const __attribute__((address_space(1))) void*)(vS1 + (size_t)kt * 64),
        (__attribute__((address_space(3))) void*)(&Vs[rb1 * 64]), 16, 0, 0);
    __syncthreads();  // vmcnt(0) drain before barrier makes DMA results visible

    // S^T = K Q^T (operand-swapped; scale+log2e folded into Q).
    // Output: lane holds S^T[key = ct*16 + quad*4 + r][q = l15].
    f32x4 s[2][4];
#pragma unroll
    for (int ct = 0; ct < 4; ct++) {
      const int row = (ct * 16 + l15) * 64;
      bf16x8 kf0 = *(const bf16x8*)&Ks[row + o0];
      bf16x8 kf1 = *(const bf16x8*)&Ks[row + o1];
#pragma unroll
      for (int grp = 0; grp < 2; grp++) {
        f32x4 z = f32x4{0.f, 0.f, 0.f, 0.f};
        z = __builtin_amdgcn_mfma_f32_16x16x32_bf16(kf0, qf0[grp], z, 0, 0, 0);
        s[grp][ct] = __builtin_amdgcn_mfma_f32_16x16x32_bf16(kf1, qf1[grp], z, 0, 0, 0);
      }
    }

    // p = 2^s; 4 consecutive keys per lane -> one packed ds_write_b64 per (grp,ct).
#pragma unroll
    for (int grp = 0; grp < 2; grp++)
#pragma unroll
      for (int ct = 0; ct < 4; ct++) {
        float p0 = __builtin_amdgcn_exp2f(s[grp][ct][0]);
        float p1 = __builtin_amdgcn_exp2f(s[grp][ct][1]);
        float p2 = __builtin_amdgcn_exp2f(s[grp][ct][2]);
        float p3 = __builtin_amdgcn_exp2f(s[grp][ct][3]);
        uint2 pw;
        pw.x = pk2(p0, p1);
        pw.y = pk2(p2, p3);
        *(uint2*)&Ps[wv][grp][l15 * 72 + ct * 16 + quad * 4] = pw;
      }

    bf16x8 pf0[2], pf1[2];
#pragma unroll
    for (int grp = 0; grp < 2; grp++) {
      pf0[grp] = *(const bf16x8*)&Ps[wv][grp][l15 * 72 + quad * 8];
      pf1[grp] = *(const bf16x8*)&Ps[wv][grp][l15 * 72 + 32 + quad * 8];
      // l row-sum via MFMA: lands in the same lane layout as acco rows
      lsum[grp] = __builtin_amdgcn_mfma_f32_16x16x32_bf16(pf0[grp], ones, lsum[grp], 0, 0, 0);
      lsum[grp] = __builtin_amdgcn_mfma_f32_16x16x32_bf16(pf1[grp], ones, lsum[grp], 0, 0, 0);
    }
    // PV: vf fragments reused across both q-groups
#pragma unroll
    for (int ni = 0; ni < 4; ni++) {
      const int row = (ni * 16 + l15) * 64;
      bf16x8 vf0 = *(const bf16x8*)&Vs[row + o0];
      bf16x8 vf1 = *(const bf16x8*)&Vs[row + o1];
#pragma unroll
      for (int grp = 0; grp < 2; grp++) {
        acco[grp][ni] = __builtin_amdgcn_mfma_f32_16x16x32_bf16(pf0[grp], vf0, acco[grp][ni], 0, 0, 0);
        acco[grp][ni] = __builtin_amdgcn_mfma_f32_16x16x32_bf16(pf1[grp], vf1, acco[grp][ni], 0, 0, 0);
      }
    }
  }

  const int b = bh >> 4, h = bh & 15;
#pragma unroll
  for (int grp = 0; grp < 2; grp++) {
    float inv[4];
#pragma unroll
    for (int r = 0; r < 4; r++) inv[r] = 1.0f / lsum[grp][r];
#pragma unroll
    for (int ni = 0; ni < 4; ni++)
#pragma unroll
      for (int r = 0; r < 4; r++) {
        size_t row = (size_t)b * 2048 + q0 + wv * 32 + grp * 16 + quad * 4 + r;
        ob[row * 1024 + h * 64 + ni * 16 + l15] = f2bf(acco[grp][ni][r] * inv[r]);
      }
  }
}

// ---------------- Output GEMM: bf16 ob [8192,1024] @ bf16 wob [1024,1024]^T + bias -> fp32 ----------------
// Both sides via global_load_lds DMA (m97 loop: 4 DMA + 8 ds_read + 16 MFMA).
// XCD remap: 512 blocks = 8 XCDs x (1 N-panel x 64 M); wob slice (256 KiB) L2-resident.
__global__ __launch_bounds__(256, 2) void gemm_out(
    const unsigned short* __restrict__ A,    // attn out bf16 [8192][1024]
    const unsigned short* __restrict__ Wo,   // w_out bf16 [1024][1024]
    const float* __restrict__ bias,          // [1024]
    float* __restrict__ out) {
  __shared__ unsigned short As[128 * 32];
  __shared__ unsigned short Bs[128 * 32];
  const int t = threadIdx.x;
  const int lane = t & 63;
  const int wv = t >> 6;
  const int wm = wv >> 1, wn = wv & 1;
  const int quad = lane >> 4, l15 = lane & 15;
  const int orig = blockIdx.x;
  const int bN = (orig & 7) * 128;
  const int bM = (orig >> 3) * 128;
  const int r0 = t >> 2;
  const int c0 = (t & 3) * 8;

  f32x4 acc[4][4];
#pragma unroll
  for (int i = 0; i < 4; i++)
#pragma unroll
    for (int j = 0; j < 4; j++) acc[i][j] = f32x4{0.f, 0.f, 0.f, 0.f};

  const unsigned short* aS0 = A + (size_t)(bM + r0) * 1024 + c0;
  const unsigned short* aS1 = A + (size_t)(bM + 64 + r0) * 1024 + c0;
  const unsigned short* bS0 = Wo + (size_t)(bN + r0) * 1024 + c0;
  const unsigned short* bS1 = Wo + (size_t)(bN + 64 + r0) * 1024 + c0;

  for (int kt = 0; kt < 32; ++kt) {
    const int k0 = kt * 32;
    __syncthreads();
    __builtin_amdgcn_global_load_lds(
        (const __attribute__((address_space(1))) void*)(aS0 + k0),
        (__attribute__((address_space(3))) void*)(&As[r0 * 32 + c0]), 16, 0, 0);
    __builtin_amdgcn_global_load_lds(
        (const __attribute__((address_space(1))) void*)(aS1 + k0),
        (__attribute__((address_space(3))) void*)(&As[(64 + r0) * 32 + c0]), 16, 0, 0);
    __builtin_amdgcn_global_load_lds(
        (const __attribute__((address_space(1))) void*)(bS0 + k0),
        (__attribute__((address_space(3))) void*)(&Bs[r0 * 32 + c0]), 16, 0, 0);
    __builtin_amdgcn_global_load_lds(
        (const __attribute__((address_space(1))) void*)(bS1 + k0),
        (__attribute__((address_space(3))) void*)(&Bs[(64 + r0) * 32 + c0]), 16, 0, 0);
    __syncthreads();

    bf16x8 af[4], bf[4];
#pragma unroll
    for (int mi = 0; mi < 4; mi++)
      af[mi] = *(const bf16x8*)&As[(wm * 64 + mi * 16 + l15) * 32 + quad * 8];
#pragma unroll
    for (int ni = 0; ni < 4; ni++)
      bf[ni] = *(const bf16x8*)&Bs[(wn * 64 + ni * 16 + l15) * 32 + quad * 8];
#pragma unroll
    for (int mi = 0; mi < 4; mi++)
#pragma unroll
      for (int ni = 0; ni < 4; ni++)
        acc[mi][ni] = __builtin_amdgcn_mfma_f32_16x16x32_bf16(af[mi], bf[ni], acc[mi][ni], 0, 0, 0);
  }

#pragma unroll
  for (int mi = 0; mi < 4; mi++) {
#pragma unroll
    for (int ni = 0; ni < 4; ni++) {
      const int n_col = bN + wn * 64 + ni * 16 + l15;
      const int m0 = bM + wm * 64 + mi * 16 + quad * 4;
      const float bv = bias[n_col];
#pragma unroll
      for (int r = 0; r < 4; r++)
        out[(size_t)(m0 + r) * 1024 + n_col] = acc[mi][ni][r] + bv;
    }
  }
}

extern "C" void kernel_launch(void* const* d_in, const int* in_sizes, int n_in,
                              void* d_out, int out_size, void* d_ws, size_t ws_size,
                              hipStream_t stream) {
  const float* x = (const float*)d_in[0];
  const float* w_qkv = (const float*)d_in[1];
  const float* b_qkv = (const float*)d_in[2];
  const float* w_out = (const float*)d_in[3];
  const float* b_out = (const float*)d_in[4];
  float* out = (float*)d_out;
  char* ws = (char*)d_ws;

  // ---- workspace layout: 32 MiB total, time-multiplexed ----
  // ws[0,16MiB):  vt (written by gemm_qkv, read by attn); after attn the first
  //               2 MiB are reused for wob (w_out bf16).
  // ws[16,32MiB): xb (x bf16, gemm_qkv A-side); dead after gemm_qkv -> ob.
  unsigned short* vt = (unsigned short*)(ws);
  unsigned short* wob = (unsigned short*)(ws);                       // after attn
  unsigned short* xb = (unsigned short*)(ws + (size_t)16 * 1024 * 1024);
  unsigned short* ob = xb;                                           // after gemm_qkv

  // ---- qb/kb live inside d_out (32 MiB): lifetime ends before gemm_out writes it ----
  unsigned short* qb = (unsigned short*)d_out;                 // 16 MiB
  unsigned short* kb = qb + (size_t)8 * 1024 * 1024;           // 16 MiB

  cvt_bf16<<<2048, 256, 0, stream>>>(x, xb, 8192 * 1024 / 4);
  gemm_qkv<<<768, 256, 0, stream>>>(xb, w_qkv, b_qkv, qb, kb, vt);
  attn<<<1024, 256, 0, stream>>>(qb, kb, vt, ob);
  cvt_bf16<<<256, 256, 0, stream>>>(w_out, wob, 1024 * 1024 / 4);
  gemm_out<<<512, 256, 0, stream>>>(ob, wob, b_out, out);
}

// Round 8
// 284.118 us; speedup vs baseline: 1.0426x; 1.0426x over previous
//
#include <hip/hip_runtime.h>
#include <hip/hip_bf16.h>
#include <cstdint>
#include <cstddef>

#define NHEADS 16
#define DHEAD 64
#define BATCH 4
#define SEQ 2048
// M = 8192, D = 1024

typedef __attribute__((ext_vector_type(8))) __bf16 bf16x8;
typedef __attribute__((ext_vector_type(4))) float f32x4;

__device__ __forceinline__ unsigned short f2bf(float f) {
  union { float f; unsigned u; } v; v.f = f;
  unsigned r = v.u + 0x7FFFu + ((v.u >> 16) & 1u);  // RNE
  return (unsigned short)(r >> 16);
}

// packed f32x2 -> bf16x2 (RNE); compiler pattern-matches to v_cvt_pk_bf16_f32
__device__ __forceinline__ unsigned pk2(float x, float y) {
  union { __hip_bfloat162 h; unsigned u; } c;
  c.h = __float22bfloat162_rn(make_float2(x, y));
  return c.u;
}

// ---------------- f32 -> bf16 convert (x4 vectorized) ----------------
__global__ void cvt_bf16(const float* __restrict__ in, unsigned short* __restrict__ out, int n4) {
  int i = blockIdx.x * blockDim.x + threadIdx.x;
  int stride = gridDim.x * blockDim.x;
  for (; i < n4; i += stride) {
    float4 f = ((const float4*)in)[i];
    uint2 o;
    o.x = pk2(f.x, f.y);
    o.y = pk2(f.z, f.w);
    ((uint2*)out)[i] = o;
  }
}

// Shared MFMA fragment-read + 4x4 accumulate (R1-proven layout; As/Bs [row][32])
#define GEMM_MFMA(Asb, Bsb)                                                       \
  do {                                                                            \
    bf16x8 af[4], bf[4];                                                          \
    _Pragma("unroll")                                                             \
    for (int mi = 0; mi < 4; mi++)                                                \
      af[mi] = *(const bf16x8*)&Asb[(wm * 64 + mi * 16 + l15) * 32 + quad * 8];   \
    _Pragma("unroll")                                                             \
    for (int ni = 0; ni < 4; ni++)                                                \
      bf[ni] = *(const bf16x8*)&Bsb[(wn * 64 + ni * 16 + l15) * 32 + quad * 8];   \
    _Pragma("unroll")                                                             \
    for (int mi = 0; mi < 4; mi++)                                                \
      _Pragma("unroll")                                                           \
      for (int ni = 0; ni < 4; ni++)                                              \
        acc[mi][ni] = __builtin_amdgcn_mfma_f32_16x16x32_bf16(af[mi], bf[ni], acc[mi][ni], 0, 0, 0); \
  } while (0)

// ---------------- QKV GEMM: bf16 xb [8192,1024] (DMA) @ f32 w_qkv [3072,1024]^T + bias ----------------
// R6-proven single-buffer 2-barrier loop (grid 1536, 16 KiB LDS) + B-side
// register prefetch: the f32 weight loads for tile kt+1 are issued in the
// post-drain slot (after barrier B, before MFMA) so their latency rides under
// the MFMA phase and is drained at the next barrier A. Correctness-safe under
// any scheduling (full __syncthreads drains guard all hazards; worst case the
// scheduler sinks the loads and we get exactly R6 behavior).
// XCD remap: each XCD owns 3 N-panels x all 64 M, m-fastest-within-3.
__global__ __launch_bounds__(256, 2) void gemm_qkv(
    const unsigned short* __restrict__ A,    // xb bf16 [8192][1024]
    const float* __restrict__ Bw,            // w_qkv f32 [3072][1024]
    const float* __restrict__ bias,          // [3072]
    unsigned short* __restrict__ qb,         // [64][2048][64]  (q pre-scaled by 0.1803369)
    unsigned short* __restrict__ kb,         // [64][2048][64]
    unsigned short* __restrict__ vt) {       // [64][64][2048]  (V^T)
  __shared__ unsigned short As[128 * 32];    // unpadded: DMA dest = base + lane*16B
  __shared__ unsigned short Bs[128 * 32];
  const int t = threadIdx.x;
  const int lane = t & 63;
  const int wv = t >> 6;
  const int wm = wv >> 1, wn = wv & 1;
  const int quad = lane >> 4, l15 = lane & 15;
  // XCD-aware remap: 1536 blocks = 8 XCDs x (3 N x 64 M)
  const int orig = blockIdx.x;
  const int xcd = orig & 7;
  const int idx = orig >> 3;            // 0..191
  const int bN = (xcd * 3 + (idx % 3)) * 128;
  const int bM = (idx / 3) * 128;
  const int r0 = t >> 2;        // 0..63
  const int c0 = (t & 3) * 8;   // 0,8,16,24

  f32x4 acc[4][4];
#pragma unroll
  for (int i = 0; i < 4; i++)
#pragma unroll
    for (int j = 0; j < 4; j++) acc[i][j] = f32x4{0.f, 0.f, 0.f, 0.f};

  const unsigned short* aS0 = A + (size_t)(bM + r0) * 1024 + c0;        // + k0
  const unsigned short* aS1 = A + (size_t)(bM + 64 + r0) * 1024 + c0;
  const size_t bR0 = (size_t)(bN + r0) * 1024 + c0;
  const size_t bR1 = (size_t)(bN + 64 + r0) * 1024 + c0;

  // prologue: B regs for tile 0
  float4 c0v = *(const float4*)&Bw[bR0];
  float4 c1v = *(const float4*)&Bw[bR0 + 4];
  float4 c2v = *(const float4*)&Bw[bR1];
  float4 c3v = *(const float4*)&Bw[bR1 + 4];

  for (int kt = 0; kt < 32; ++kt) {
    const int k0 = kt * 32;
    const int k1 = (kt < 31 ? kt + 1 : 31) * 32;   // clamped: last iter reloads own tile (discarded)
    __syncthreads();  // A: prev readers done; drains the prefetch loads (hidden under prev MFMA)
    __builtin_amdgcn_global_load_lds(
        (const __attribute__((address_space(1))) void*)(aS0 + k0),
        (__attribute__((address_space(3))) void*)(&As[r0 * 32 + c0]), 16, 0, 0);
    __builtin_amdgcn_global_load_lds(
        (const __attribute__((address_space(1))) void*)(aS1 + k0),
        (__attribute__((address_space(3))) void*)(&As[(64 + r0) * 32 + c0]), 16, 0, 0);
    // stage Bs from already-loaded regs (no vmem wait on this path)
    uint4 w0, w1;
    w0.x = pk2(c0v.x, c0v.y); w0.y = pk2(c0v.z, c0v.w);
    w0.z = pk2(c1v.x, c1v.y); w0.w = pk2(c1v.z, c1v.w);
    w1.x = pk2(c2v.x, c2v.y); w1.y = pk2(c2v.z, c2v.w);
    w1.z = pk2(c3v.x, c3v.y); w1.w = pk2(c3v.z, c3v.w);
    *(uint4*)&Bs[r0 * 32 + c0] = w0;
    *(uint4*)&Bs[(64 + r0) * 32 + c0] = w1;
    __syncthreads();  // B: drains DMA (vmcnt) + LDS writes (lgkm)

    // issue next-tile B loads; in flight across the MFMA phase
    float4 n0 = *(const float4*)&Bw[bR0 + k1];
    float4 n1 = *(const float4*)&Bw[bR0 + k1 + 4];
    float4 n2 = *(const float4*)&Bw[bR1 + k1];
    float4 n3 = *(const float4*)&Bw[bR1 + k1 + 4];
    __builtin_amdgcn_sched_barrier(0);  // pin issue point above the MFMA cluster

    GEMM_MFMA(As, Bs);

    c0v = n0; c1v = n1; c2v = n2; c3v = n3;
  }

  // epilogue: C row = bM+wm*64+mi*16+quad*4+reg, col = bN+wn*64+ni*16+l15
#pragma unroll
  for (int mi = 0; mi < 4; mi++) {
#pragma unroll
    for (int ni = 0; ni < 4; ni++) {
      const int n_col = bN + wn * 64 + ni * 16 + l15;
      const int m0 = bM + wm * 64 + mi * 16 + quad * 4;  // multiple of 4; all 4 rows same batch
      const float bv = bias[n_col];
      const int s = n_col >> 10;          // wave-uniform (16-col groups aligned)
      const int rem = n_col & 1023;
      const int h = rem >> 6, d = rem & 63;
      const int b = m0 >> 11;
      const int nn = m0 & 2047;
      const int bh = b * 16 + h;
      if (s == 2) {
        ushort4 o;
        o.x = f2bf(acc[mi][ni][0] + bv);
        o.y = f2bf(acc[mi][ni][1] + bv);
        o.z = f2bf(acc[mi][ni][2] + bv);
        o.w = f2bf(acc[mi][ni][3] + bv);
        *(ushort4*)&vt[((size_t)bh * 64 + d) * 2048 + nn] = o;
      } else {
        unsigned short* dst = (s == 0) ? qb : kb;
        // q scale = 1/8 (1/sqrt(dh)) * log2(e), so attn uses exp2 directly
        const float scale = (s == 0) ? 0.18033688f : 1.0f;
#pragma unroll
        for (int r = 0; r < 4; r++) {
          float v = (acc[mi][ni][r] + bv) * scale;
          dst[((size_t)bh * 2048 + nn + r) * 64 + d] = f2bf(v);
        }
      }
    }
  }
}

// ---------------- Flash attention: per (bh, 128 q-rows) block ----------------
// Proven R1 structure (passed @94us): single-buffer, two __syncthreads per kt.
// XCD remap: each XCD owns 8 bh x 16 q-blocks, q-fastest -> each bh's K/V
// (512 KiB) is fetched by exactly one XCD and stays L2-resident.
__global__ __launch_bounds__(256, 4) void attn(const unsigned short* __restrict__ qb,
                                               const unsigned short* __restrict__ kb,
                                               const unsigned short* __restrict__ vt,
                                               unsigned short* __restrict__ ob) {
  __shared__ unsigned short Ks[64 * 64];      // [key][d-group swizzled]
  __shared__ unsigned short Vs[64 * 64];      // [d][key-group swizzled]
  __shared__ unsigned short Ps[4][2][16 * 72];
  // XCD-aware remap: 1024 blocks = 8 XCDs x (8 bh x 16 q)
  const int orig = blockIdx.x;
  const int xcd = orig & 7;
  const int idx = orig >> 3;            // 0..127
  const int bh = xcd * 8 + (idx >> 4);  // 0..63
  const int q0 = (idx & 15) * 128;
  const int t = threadIdx.x, lane = t & 63, wv = t >> 6;
  const int quad = lane >> 4, l15 = lane & 15;
  const int ri = lane >> 3;    // 0..7: row within an 8-row DMA group
  const int g = lane & 7;      // 0..7: 16B group within a row
  const int sg = g ^ ri;       // swizzled source group

  // Q fragments for both 16-row groups, direct from global (B-operand layout)
  bf16x8 qf0[2], qf1[2];
#pragma unroll
  for (int grp = 0; grp < 2; grp++) {
    const size_t qbase = ((size_t)bh * 2048 + q0 + wv * 32 + grp * 16 + l15) * 64 + quad * 8;
    qf0[grp] = *(const bf16x8*)&qb[qbase];
    qf1[grp] = *(const bf16x8*)&qb[qbase + 32];
  }

  // DMA sources: wave wv loads rows [wv*16, wv*16+16) of each 64x64 tile
  const int rb0 = wv * 16;
  const int rb1 = wv * 16 + 8;
  const unsigned short* kS0 = kb + ((size_t)bh * 2048 + rb0 + ri) * 64 + sg * 8;  // +kt*4096
  const unsigned short* kS1 = kb + ((size_t)bh * 2048 + rb1 + ri) * 64 + sg * 8;
  const unsigned short* vS0 = vt + ((size_t)bh * 64 + rb0 + ri) * 2048 + sg * 8;  // +kt*64
  const unsigned short* vS1 = vt + ((size_t)bh * 64 + rb1 + ri) * 2048 + sg * 8;

  // lane-constant swizzled fragment read offsets (elements)
  const int o0 = (quad ^ (l15 & 7)) * 8;
  const int o1 = ((quad + 4) ^ (l15 & 7)) * 8;

  // all-ones B fragment for the l row-sum MFMA
  bf16x8 ones;
#pragma unroll
  for (int i = 0; i < 8; i++) ones[i] = (__bf16)1.0f;

  f32x4 acco[2][4];
#pragma unroll
  for (int grp = 0; grp < 2; grp++)
#pragma unroll
    for (int i = 0; i < 4; i++) acco[grp][i] = f32x4{0.f, 0.f, 0.f, 0.f};
  f32x4 lsum[2];
  lsum[0] = f32x4{0.f, 0.f, 0.f, 0.f};
  lsum[1] = f32x4{0.f, 0.f, 0.f, 0.f};

  for (int kt = 0; kt < 32; ++kt) {
    __syncthreads();  // previous iteration's readers done before DMA overwrites
    __builtin_amdgcn_global_load_lds(
        (const __attribute__((address_space(1))) void*)(kS0 + (size_t)kt * 4096),
        (__attribute__((address_space(3))) void*)(&Ks[rb0 * 64]), 16, 0, 0);
    __builtin_amdgcn_global_load_lds(
        (const __attribute__((address_space(1))) void*)(kS1 + (size_t)kt * 4096),
        (__attribute__((address_space(3))) void*)(&Ks[rb1 * 64]), 16, 0, 0);
    __builtin_amdgcn_global_load_lds(
        (const __attribute__((address_space(1))) void*)(vS0 + (size_t)kt * 64),
        (__attribute__((address_space(3))) void*)(&Vs[rb0 * 64]), 16, 0, 0);
    __builtin_amdgcn_global_load_lds(
        (const __attribute__((address_space(1))) void*)(vS1 + (size_t)kt * 64),
        (__attribute__((address_space(3))) void*)(&Vs[rb1 * 64]), 16, 0, 0);
    __syncthreads();  // vmcnt(0) drain before barrier makes DMA results visible

    // S^T = K Q^T (operand-swapped; scale+log2e folded into Q).
    // Output: lane holds S^T[key = ct*16 + quad*4 + r][q = l15].
    f32x4 s[2][4];
#pragma unroll
    for (int ct = 0; ct < 4; ct++) {
      const int row = (ct * 16 + l15) * 64;
      bf16x8 kf0 = *(const bf16x8*)&Ks[row + o0];
      bf16x8 kf1 = *(const bf16x8*)&Ks[row + o1];
#pragma unroll
      for (int grp = 0; grp < 2; grp++) {
        f32x4 z = f32x4{0.f, 0.f, 0.f, 0.f};
        z = __builtin_amdgcn_mfma_f32_16x16x32_bf16(kf0, qf0[grp], z, 0, 0, 0);
        s[grp][ct] = __builtin_amdgcn_mfma_f32_16x16x32_bf16(kf1, qf1[grp], z, 0, 0, 0);
      }
    }

    // p = 2^s; 4 consecutive keys per lane -> one packed ds_write_b64 per (grp,ct).
#pragma unroll
    for (int grp = 0; grp < 2; grp++)
#pragma unroll
      for (int ct = 0; ct < 4; ct++) {
        float p0 = __builtin_amdgcn_exp2f(s[grp][ct][0]);
        float p1 = __builtin_amdgcn_exp2f(s[grp][ct][1]);
        float p2 = __builtin_amdgcn_exp2f(s[grp][ct][2]);
        float p3 = __builtin_amdgcn_exp2f(s[grp][ct][3]);
        uint2 pw;
        pw.x = pk2(p0, p1);
        pw.y = pk2(p2, p3);
        *(uint2*)&Ps[wv][grp][l15 * 72 + ct * 16 + quad * 4] = pw;
      }

    bf16x8 pf0[2], pf1[2];
#pragma unroll
    for (int grp = 0; grp < 2; grp++) {
      pf0[grp] = *(const bf16x8*)&Ps[wv][grp][l15 * 72 + quad * 8];
      pf1[grp] = *(const bf16x8*)&Ps[wv][grp][l15 * 72 + 32 + quad * 8];
      // l row-sum via MFMA: lands in the same lane layout as acco rows
      lsum[grp] = __builtin_amdgcn_mfma_f32_16x16x32_bf16(pf0[grp], ones, lsum[grp], 0, 0, 0);
      lsum[grp] = __builtin_amdgcn_mfma_f32_16x16x32_bf16(pf1[grp], ones, lsum[grp], 0, 0, 0);
    }
    // PV: vf fragments reused across both q-groups
#pragma unroll
    for (int ni = 0; ni < 4; ni++) {
      const int row = (ni * 16 + l15) * 64;
      bf16x8 vf0 = *(const bf16x8*)&Vs[row + o0];
      bf16x8 vf1 = *(const bf16x8*)&Vs[row + o1];
#pragma unroll
      for (int grp = 0; grp < 2; grp++) {
        acco[grp][ni] = __builtin_amdgcn_mfma_f32_16x16x32_bf16(pf0[grp], vf0, acco[grp][ni], 0, 0, 0);
        acco[grp][ni] = __builtin_amdgcn_mfma_f32_16x16x32_bf16(pf1[grp], vf1, acco[grp][ni], 0, 0, 0);
      }
    }
  }

  const int b = bh >> 4, h = bh & 15;
#pragma unroll
  for (int grp = 0; grp < 2; grp++) {
    float inv[4];
#pragma unroll
    for (int r = 0; r < 4; r++) inv[r] = 1.0f / lsum[grp][r];
#pragma unroll
    for (int ni = 0; ni < 4; ni++)
#pragma unroll
      for (int r = 0; r < 4; r++) {
        size_t row = (size_t)b * 2048 + q0 + wv * 32 + grp * 16 + quad * 4 + r;
        ob[row * 1024 + h * 64 + ni * 16 + l15] = f2bf(acco[grp][ni][r] * inv[r]);
      }
  }
}

// ---------------- Output GEMM: bf16 ob [8192,1024] @ bf16 wob [1024,1024]^T + bias -> fp32 ----------------
// Both sides via global_load_lds DMA (m97 loop: 4 DMA + 8 ds_read + 16 MFMA).
// XCD remap: 512 blocks = 8 XCDs x (1 N-panel x 64 M); wob slice (256 KiB) L2-resident.
__global__ __launch_bounds__(256, 2) void gemm_out(
    const unsigned short* __restrict__ A,    // attn out bf16 [8192][1024]
    const unsigned short* __restrict__ Wo,   // w_out bf16 [1024][1024]
    const float* __restrict__ bias,          // [1024]
    float* __restrict__ out) {
  __shared__ unsigned short As[128 * 32];
  __shared__ unsigned short Bs[128 * 32];
  const int t = threadIdx.x;
  const int lane = t & 63;
  const int wv = t >> 6;
  const int wm = wv >> 1, wn = wv & 1;
  const int quad = lane >> 4, l15 = lane & 15;
  const int orig = blockIdx.x;
  const int bN = (orig & 7) * 128;
  const int bM = (orig >> 3) * 128;
  const int r0 = t >> 2;
  const int c0 = (t & 3) * 8;

  f32x4 acc[4][4];
#pragma unroll
  for (int i = 0; i < 4; i++)
#pragma unroll
    for (int j = 0; j < 4; j++) acc[i][j] = f32x4{0.f, 0.f, 0.f, 0.f};

  const unsigned short* aS0 = A + (size_t)(bM + r0) * 1024 + c0;
  const unsigned short* aS1 = A + (size_t)(bM + 64 + r0) * 1024 + c0;
  const unsigned short* bS0 = Wo + (size_t)(bN + r0) * 1024 + c0;
  const unsigned short* bS1 = Wo + (size_t)(bN + 64 + r0) * 1024 + c0;

  for (int kt = 0; kt < 32; ++kt) {
    const int k0 = kt * 32;
    __syncthreads();
    __builtin_amdgcn_global_load_lds(
        (const __attribute__((address_space(1))) void*)(aS0 + k0),
        (__attribute__((address_space(3))) void*)(&As[r0 * 32 + c0]), 16, 0, 0);
    __builtin_amdgcn_global_load_lds(
        (const __attribute__((address_space(1))) void*)(aS1 + k0),
        (__attribute__((address_space(3))) void*)(&As[(64 + r0) * 32 + c0]), 16, 0, 0);
    __builtin_amdgcn_global_load_lds(
        (const __attribute__((address_space(1))) void*)(bS0 + k0),
        (__attribute__((address_space(3))) void*)(&Bs[r0 * 32 + c0]), 16, 0, 0);
    __builtin_amdgcn_global_load_lds(
        (const __attribute__((address_space(1))) void*)(bS1 + k0),
        (__attribute__((address_space(3))) void*)(&Bs[(64 + r0) * 32 + c0]), 16, 0, 0);
    __syncthreads();

    GEMM_MFMA(As, Bs);
  }

#pragma unroll
  for (int mi = 0; mi < 4; mi++) {
#pragma unroll
    for (int ni = 0; ni < 4; ni++) {
      const int n_col = bN + wn * 64 + ni * 16 + l15;
      const int m0 = bM + wm * 64 + mi * 16 + quad * 4;
      const float bv = bias[n_col];
#pragma unroll
      for (int r = 0; r < 4; r++)
        out[(size_t)(m0 + r) * 1024 + n_col] = acc[mi][ni][r] + bv;
    }
  }
}

extern "C" void kernel_launch(void* const* d_in, const int* in_sizes, int n_in,
                              void* d_out, int out_size, void* d_ws, size_t ws_size,
                              hipStream_t stream) {
  const float* x = (const float*)d_in[0];
  const float* w_qkv = (const float*)d_in[1];
  const float* b_qkv = (const float*)d_in[2];
  const float* w_out = (const float*)d_in[3];
  const float* b_out = (const float*)d_in[4];
  float* out = (float*)d_out;
  char* ws = (char*)d_ws;

  // ---- workspace layout: 32 MiB total, time-multiplexed ----
  // ws[0,16MiB):  vt (written by gemm_qkv, read by attn); after attn the first
  //               2 MiB are reused for wob (w_out bf16).
  // ws[16,32MiB): xb (x bf16, gemm_qkv A-side); dead after gemm_qkv -> ob.
  unsigned short* vt = (unsigned short*)(ws);
  unsigned short* wob = (unsigned short*)(ws);                       // after attn
  unsigned short* xb = (unsigned short*)(ws + (size_t)16 * 1024 * 1024);
  unsigned short* ob = xb;                                           // after gemm_qkv

  // ---- qb/kb live inside d_out (32 MiB): lifetime ends before gemm_out writes it ----
  unsigned short* qb = (unsigned short*)d_out;                 // 16 MiB
  unsigned short* kb = qb + (size_t)8 * 1024 * 1024;           // 16 MiB

  cvt_bf16<<<2048, 256, 0, stream>>>(x, xb, 8192 * 1024 / 4);
  gemm_qkv<<<1536, 256, 0, stream>>>(xb, w_qkv, b_qkv, qb, kb, vt);
  attn<<<1024, 256, 0, stream>>>(qb, kb, vt, ob);
  cvt_bf16<<<256, 256, 0, stream>>>(w_out, wob, 1024 * 1024 / 4);
  gemm_out<<<512, 256, 0, stream>>>(ob, wob, b_out, out);
}